// Round 5
// baseline (303.958 us; speedup 1.0000x reference)
//
#include <hip/hip_runtime.h>

// x[B][C][H][W] fp32, weight[C][1][H][1], bias[C]
// out[b,c,h,w] = sum_k w_c[k] * x[b,c,(h+k)%56,w] + bias[c]
// Rewritten as per-plane circulant matmul: out = M_c @ x_plane,
// M_c[h][j] = w_c[(j-h) mod 56], padded 56->64, bf16 MFMA 16x16x32.
#define NB 32
#define NC 384
#define NH 56
#define NW 56
#define HP 64          // padded H/J/W dim

typedef __attribute__((ext_vector_type(8))) short  bf16x8;
typedef __attribute__((ext_vector_type(4))) float  f32x4;
typedef __attribute__((ext_vector_type(4))) unsigned int u32x4;

__device__ __forceinline__ unsigned short f2bf(float f) {
    unsigned u = __float_as_uint(f);                 // RNE float->bf16
    return (unsigned short)((u + 0x7FFFu + ((u >> 16) & 1u)) >> 16);
}

// Block = one c, 4 b-planes (one per wave). grid = NC*8, block = 256.
__global__ __launch_bounds__(256, 4) void gcc_Conv2d_64347200028713_kernel(
    const float* __restrict__ x,
    const float* __restrict__ wgt,
    const float* __restrict__ bias,
    float* __restrict__ out)
{
    const int tid  = threadIdx.x;
    const int lane = tid & 63;
    const int wave = tid >> 6;
    const int c    = blockIdx.x >> 3;       // 0..383
    const int g    = blockIdx.x & 7;        // 0..7
    const int b    = g * 4 + wave;          // 0..31
    const int plane = b * NC + c;

    __shared__ float wsh[NH];
    __shared__ __align__(16) unsigned short Mw[HP * HP];        // M[h][j] bf16, 8 KB
    __shared__ __align__(16) unsigned short Xw_all[4][HP * HP]; // per-wave x[j][w] bf16, 32 KB

    // ---- stage weights, build M_c (once per block) ----
    if (tid < NH) wsh[tid] = wgt[c * NH + tid];
    __syncthreads();
#pragma unroll
    for (int i = tid; i < HP * HP; i += 256) {
        const int h = i >> 6, j = i & 63;
        unsigned short v = 0;
        if (h < NH && j < NH) { int d = j - h; if (d < 0) d += NH; v = f2bf(wsh[d]); }
        Mw[i] = v;
    }
    __syncthreads();

    // ---- stage this wave's x plane into Xw[j][w] (bf16), zero j-pad ----
    unsigned short* Xw = Xw_all[wave];
    const float* __restrict__ xp = x + (size_t)plane * (NH * NW);

    {   // zero rows j = 56..63 (1024 B): 16 B per lane
        u32x4 z = {0u, 0u, 0u, 0u};
        *reinterpret_cast<u32x4*>(&Xw[NH * HP + lane * 8]) = z;
    }
    if (lane < 56) {
        const int jin = lane / 14;          // 0..3
        const int wq  = lane % 14;          // 0..13 (w = wq*4..+4)
#pragma unroll
        for (int it = 0; it < 14; ++it) {
            const int j = it * 4 + jin;     // 0..55
            const float4 v = *reinterpret_cast<const float4*>(xp + j * NW + wq * 4);
            const unsigned lo = (unsigned)f2bf(v.x) | ((unsigned)f2bf(v.y) << 16);
            const unsigned hi = (unsigned)f2bf(v.z) | ((unsigned)f2bf(v.w) << 16);
            const unsigned long long pk = ((unsigned long long)hi << 32) | lo;
            *reinterpret_cast<unsigned long long*>(&Xw[j * HP + wq * 4]) = pk;
        }
    }
    // (w cols 56..63 of real rows stay junk: they only feed C cols >=56, never stored.
    //  j rows 56..63 zeroed above; M cols j>=56 are zero -> no 0*NaN anywhere stored.)

    const int l15 = lane & 15;              // 16-index within fragments
    const int kg  = lane >> 4;              // k-group 0..3
    const float bc = bias[c];
    float* __restrict__ op = out + (size_t)plane * (NH * NW);

    // ---- compute: two wt-halves to keep acc at 32 VGPR ----
#pragma unroll
    for (int half = 0; half < 2; ++half) {
        f32x4 acc[4][2] = {};               // [ht][wtl]
#pragma unroll
        for (int kk = 0; kk < 2; ++kk) {
            bf16x8 af[4];
#pragma unroll
            for (int ht = 0; ht < 4; ++ht)
                af[ht] = *reinterpret_cast<const bf16x8*>(
                    &Mw[(ht * 16 + l15) * HP + kk * 32 + kg * 8]);
#pragma unroll
            for (int wtl = 0; wtl < 2; ++wtl) {
                const int n = (half * 2 + wtl) * 16 + l15;   // w column
                bf16x8 bf;
#pragma unroll
                for (int e = 0; e < 8; ++e)
                    bf[e] = (short)Xw[(kk * 32 + kg * 8 + e) * HP + n];
#pragma unroll
                for (int ht = 0; ht < 4; ++ht)
                    acc[ht][wtl] = __builtin_amdgcn_mfma_f32_16x16x32_bf16(
                        af[ht], bf, acc[ht][wtl], 0, 0, 0);
            }
        }
        // ---- store this half's columns ----
#pragma unroll
        for (int ht = 0; ht < 4; ++ht) {
#pragma unroll
            for (int wtl = 0; wtl < 2; ++wtl) {
                const int ww = (half * 2 + wtl) * 16 + l15;
#pragma unroll
                for (int r = 0; r < 4; ++r) {
                    const int hh = ht * 16 + kg * 4 + r;
                    if (hh < NH && ww < NW)
                        op[hh * NW + ww] = acc[ht][wtl][r] + bc;
                }
            }
        }
    }
}

extern "C" void kernel_launch(void* const* d_in, const int* in_sizes, int n_in,
                              void* d_out, int out_size, void* d_ws, size_t ws_size,
                              hipStream_t stream)
{
    const float* x    = (const float*)d_in[0];
    const float* wgt  = (const float*)d_in[1];
    const float* bias = (const float*)d_in[2];
    float* out        = (float*)d_out;

    const int grid  = NC * 8;   // 3072 blocks: (c, 8 groups of 4 b-planes)
    const int block = 256;      // 4 waves

    gcc_Conv2d_64347200028713_kernel<<<grid, block, 0, stream>>>(x, wgt, bias, out);
}